// Round 13
// baseline (333.526 us; speedup 1.0000x reference)
//
#include <hip/hip_runtime.h>
#include <hip/hip_bf16.h>

// Problem constants
#define NB 4
#define NT 256
#define NU 100
#define NH 512      // H_ENC = H_DEC = 512
#define NI 512      // INNER
#define NV 1024     // VOCAB
#define MROWS (NB * NT * NU)   // 102400 joint rows

typedef __attribute__((ext_vector_type(4))) float f32x4;
typedef __attribute__((ext_vector_type(8))) __bf16 bf16x8;

// round-to-nearest-even f32 -> bf16 bits
static __device__ __forceinline__ unsigned int f2bf(float f) {
  unsigned int u = __float_as_uint(f);
  return (u + 0x7FFFu + ((u >> 16) & 1u)) >> 16;
}

// tanh(x) = 1 - 2/(1+e^{2x})
static __device__ __forceinline__ float fast_tanh(float x) {
  float e = __expf(2.f * x);
  return 1.f - 2.f * __builtin_amdgcn_rcpf(1.f + e);
}

// packed RNE f32x2 -> bf16x2 (single instruction)
static __device__ __forceinline__ unsigned int cvt_pk_bf16(float lo, float hi) {
  unsigned int r;
  asm("v_cvt_pk_bf16_f32 %0, %1, %2" : "=v"(r) : "v"(lo), "v"(hi));
  return r;
}

// async global->LDS, 16B per lane
static __device__ __forceinline__ void gload16(const void* g, void* l) {
  __builtin_amdgcn_global_load_lds(
      (const __attribute__((address_space(1))) unsigned int*)(g),
      (__attribute__((address_space(3))) unsigned int*)(l), 16, 0, 0);
}

// ---------------------------------------------------------------------------
// Merged projections: pe[r][i] = enc[r][:] . W1[i][0:512]   (r < 1024)
//                     pd[r][i] = dec[r][:] . W1[i][512:1024] (r < 400)
// ---------------------------------------------------------------------------
__global__ __launch_bounds__(256) void proj_kernel(
    const float* __restrict__ enc, const float* __restrict__ dec,
    const float* __restrict__ W1, float* __restrict__ pe, float* __restrict__ pd) {
  __shared__ float As[64][17];
  __shared__ float Bs[64][17];
  const int bx = blockIdx.x;
  const float* A;
  float* P;
  int Mrows, colOff, row0;
  if (bx < 16) { A = enc; P = pe; Mrows = NB * NT; colOff = 0;  row0 = bx * 64; }
  else         { A = dec; P = pd; Mrows = NB * NU; colOff = NH; row0 = (bx - 16) * 64; }
  const int col0 = blockIdx.y * 64;
  const int tx = threadIdx.x;
  const int tr = tx >> 4, tc = tx & 15;
  const int lr = tx >> 2, lc = (tx & 3) * 4;
  float acc[4][4] = {};
  for (int k0 = 0; k0 < NH; k0 += 16) {
    float4 av = make_float4(0.f, 0.f, 0.f, 0.f);
    if (row0 + lr < Mrows)
      av = *(const float4*)(A + (size_t)(row0 + lr) * NH + k0 + lc);
    float4 bv = *(const float4*)(W1 + (size_t)(col0 + lr) * (NH + NH) + colOff + k0 + lc);
    As[lr][lc] = av.x; As[lr][lc + 1] = av.y; As[lr][lc + 2] = av.z; As[lr][lc + 3] = av.w;
    Bs[lr][lc] = bv.x; Bs[lr][lc + 1] = bv.y; Bs[lr][lc + 2] = bv.z; Bs[lr][lc + 3] = bv.w;
    __syncthreads();
#pragma unroll
    for (int kk = 0; kk < 16; ++kk) {
      float a4[4], b4[4];
#pragma unroll
      for (int i = 0; i < 4; ++i) { a4[i] = As[tr * 4 + i][kk]; b4[i] = Bs[tc * 4 + i][kk]; }
#pragma unroll
      for (int i = 0; i < 4; ++i)
#pragma unroll
        for (int j = 0; j < 4; ++j) acc[i][j] = fmaf(a4[i], b4[j], acc[i][j]);
    }
    __syncthreads();
  }
#pragma unroll
  for (int i = 0; i < 4; ++i) {
    int r = row0 + tr * 4 + i;
    if (r < Mrows) {
#pragma unroll
      for (int j = 0; j < 4; ++j)
        P[(size_t)r * NI + col0 + tc * 4 + j] = acc[i][j];
    }
  }
}

// ---------------------------------------------------------------------------
// W2 f32 -> bf16, PRE-FRAGGED for BK=32 linear LDS staging/reads:
// chunk g (16B) = [nt 4][kt 16][cb 16][lq 4][lr 16] ->
//   v = nt*256 + cb*16 + lr,  k = kt*32 + lq*8
// ---------------------------------------------------------------------------
__global__ __launch_bounds__(256) void cvt_w2_frag_kernel(
    const float* __restrict__ W2, unsigned short* __restrict__ w2f) {
  int g = blockIdx.x * 256 + threadIdx.x;      // 65536 chunks
  int lr = g & 15, lq = (g >> 4) & 3;
  int cb = (g >> 6) & 15, kt = (g >> 10) & 15, nt = (g >> 14) & 3;
  int v = nt * 256 + cb * 16 + lr;
  int k = kt * 32 + lq * 8;
  const float* src = W2 + (size_t)v * NI + k;
  float4 a = *(const float4*)src;
  float4 b = *(const float4*)(src + 4);
  uint4 o;
  o.x = f2bf(a.x) | (f2bf(a.y) << 16);
  o.y = f2bf(a.z) | (f2bf(a.w) << 16);
  o.z = f2bf(b.x) | (f2bf(b.y) << 16);
  o.w = f2bf(b.z) | (f2bf(b.w) << 16);
  *(uint4*)(w2f + (size_t)g * 8) = o;
}

// ---------------------------------------------------------------------------
// Fused joint GEMM: tanh once, B staged to LDS once per block.
// Block: 512 thr / 8 waves (2M x 4N), 128 rows x FULL 1024 vocab.
// LDS 160 KB: A panel 128x512 bf16 = 128 KB (computed in phase 0, XOR-
//   swizzled granules) + B ring 2 x 16 KB (256-col panel x BK=32 tiles,
//   global_load_lds from pre-fragged w2f -> wave-linear, 0 conflicts).
// K-loop g = 0..63 (np = g>>4 vocab panel, kt = g&15):
//   STAGE(g+1 -> other slot): 2 x gload16 / thread (16 KB)
//   8 x ds_read_b128 (af x4 from A, bfv x4 from B slot) + 16 MFMA
//   if kt==15: epilogue stores for panel np (no drain)
//   __syncthreads (single per step; stage has ~600 cy MFMA shadow)
// Wave tile 64x64 -> ds:MFMA = 0.5. B L2 traffic: 1 MB/block (was 8 MB).
// ---------------------------------------------------------------------------
__global__ __launch_bounds__(512, 2) void fused_joint_kernel(
    const float* __restrict__ pe, const float* __restrict__ pd,
    const float* __restrict__ b1, const unsigned short* __restrict__ w2f,
    const float* __restrict__ b2, float* __restrict__ out) {
  __shared__ unsigned char ldsA[131072];   // 128 rows x 512 k bf16, swizzled
  __shared__ unsigned char ldsB[32768];    // 2 slots x 16 KB (256c x 32k)
  const int tx = threadIdx.x;
  const int R0 = blockIdx.x * 128;
  const int lane = tx & 63, wid = tx >> 6;
  const int wr = wid >> 2, wc = wid & 3;   // 2M x 4N; wave tile 64 x 64
  const int lr = lane & 15, lq = lane >> 4;

  // B stage: tile (np,kt) = 1024 chunks at w2f[((np*16+kt)<<10)*8]
#define STAGEB(G, SLOT) do {                                                  \
    unsigned char* dB_ = ldsB + (SLOT) * 16384;                               \
    const unsigned char* src_ = (const unsigned char*)w2f + ((size_t)(G) << 14); \
    gload16(src_ + tx * 16, dB_ + tx * 16);                                   \
    gload16(src_ + (512 + tx) * 16, dB_ + (512 + tx) * 16);                   \
  } while (0)

  STAGEB(0, 0);                            // in flight through phase 0

  // ---- Phase 0: A panel (128 x 512) = tanh(pe+pd+b1) -> ldsA ----
#pragma unroll 2
  for (int pass = 0; pass < 16; ++pass) {
    int idx = pass * 512 + tx;             // 8192 granules of 8 elems
    int row = idx >> 6;                    // 0..127
    int g8 = idx & 63;                     // granule within row
    int i0 = g8 * 8;
    int grow = R0 + row;
    int b = grow / (NT * NU);
    int rem = grow - b * (NT * NU);
    int t = rem / NU;
    int u = rem - t * NU;
    const float* peP = pe + (size_t)(b * NT + t) * NI + i0;
    const float* pdP = pd + (size_t)(b * NU + u) * NI + i0;
    float4 p0 = *(const float4*)peP, p1 = *(const float4*)(peP + 4);
    float4 q0 = *(const float4*)pdP, q1 = *(const float4*)(pdP + 4);
    float4 c0 = *(const float4*)(b1 + i0), c1 = *(const float4*)(b1 + i0 + 4);
    uint4 pk;
    pk.x = cvt_pk_bf16(fast_tanh(p0.x + q0.x + c0.x), fast_tanh(p0.y + q0.y + c0.y));
    pk.y = cvt_pk_bf16(fast_tanh(p0.z + q0.z + c0.z), fast_tanh(p0.w + q0.w + c0.w));
    pk.z = cvt_pk_bf16(fast_tanh(p1.x + q1.x + c1.x), fast_tanh(p1.y + q1.y + c1.y));
    pk.w = cvt_pk_bf16(fast_tanh(p1.z + q1.z + c1.z), fast_tanh(p1.w + q1.w + c1.w));
    *(uint4*)(ldsA + row * 1024 + ((g8 ^ (row & 7)) << 4)) = pk;
  }
  __syncthreads();                         // drains phase-0 writes + STAGEB(0)

  f32x4 acc[4][4];
#pragma unroll
  for (int mf = 0; mf < 4; ++mf)
#pragma unroll
    for (int nf = 0; nf < 4; ++nf)
#pragma unroll
      for (int z = 0; z < 4; ++z) acc[mf][nf][z] = 0.f;

  for (int g = 0; g < 64; ++g) {
    const int kt = g & 15, slot = g & 1;
    if (g < 63) STAGEB(g + 1, slot ^ 1);   // in flight during MFMA below
    const unsigned char* Bb = ldsB + slot * 16384;

    bf16x8 af4[4], bfv[4];
#pragma unroll
    for (int nf = 0; nf < 4; ++nf)
      bfv[nf] = *(const bf16x8*)(Bb + ((wc * 4 + nf) * 64 + lq * 16 + lr) * 16);
#pragma unroll
    for (int mf = 0; mf < 4; ++mf) {
      int row = wr * 64 + mf * 16 + lr;
      af4[mf] = *(const bf16x8*)(ldsA + row * 1024 +
                                 (((kt * 4 + lq) ^ (row & 7)) << 4));
    }
    __builtin_amdgcn_s_setprio(1);
#pragma unroll
    for (int mf = 0; mf < 4; ++mf)
#pragma unroll
      for (int nf = 0; nf < 4; ++nf)
        acc[mf][nf] = __builtin_amdgcn_mfma_f32_16x16x32_bf16(
            af4[mf], bfv[nf], acc[mf][nf], 0, 0, 0);
    __builtin_amdgcn_s_setprio(0);

    if (kt == 15) {
      const int np = g >> 4;
#pragma unroll
      for (int nf = 0; nf < 4; ++nf) {
        int col = np * 256 + wc * 64 + nf * 16 + lr;
        float bb = b2[col];
#pragma unroll
        for (int mf = 0; mf < 4; ++mf) {
#pragma unroll
          for (int j = 0; j < 4; ++j) {
            int grow = R0 + wr * 64 + mf * 16 + lq * 4 + j;
            out[(size_t)grow * NV + col] = acc[mf][nf][j] + bb;
            acc[mf][nf][j] = 0.f;
          }
        }
      }
    }
    if (g < 63) __syncthreads();           // single barrier per step
  }
#undef STAGEB
}

extern "C" void kernel_launch(void* const* d_in, const int* in_sizes, int n_in,
                              void* d_out, int out_size, void* d_ws, size_t ws_size,
                              hipStream_t stream) {
  const float* enc = (const float*)d_in[0];
  const float* dec = (const float*)d_in[1];
  const float* W1  = (const float*)d_in[2];
  const float* b1  = (const float*)d_in[3];
  const float* W2  = (const float*)d_in[4];
  const float* b2  = (const float*)d_in[5];
  float* out = (float*)d_out;
  char* ws = (char*)d_ws;

  float* pe = (float*)ws;                                   // 2 MB
  float* pd = (float*)(ws + (2u << 20));                    // 0.8 MB
  unsigned short* w2f = (unsigned short*)(ws + (3u << 20)); // 1 MB, fragged

  proj_kernel<<<dim3(23, 8), 256, 0, stream>>>(enc, dec, W1, pe, pd);
  cvt_w2_frag_kernel<<<256, 256, 0, stream>>>(W2, w2f);
  fused_joint_kernel<<<MROWS / 128, 512, 0, stream>>>(pe, pd, b1, w2f, b2, out);
}

// Round 14
// 262.491 us; speedup vs baseline: 1.2706x; 1.2706x over previous
//
#include <hip/hip_runtime.h>
#include <hip/hip_bf16.h>

// Problem constants
#define NB 4
#define NT 256
#define NU 100
#define NH 512      // H_ENC = H_DEC = 512
#define NI 512      // INNER
#define NV 1024     // VOCAB
#define MROWS (NB * NT * NU)   // 102400 joint rows

typedef __attribute__((ext_vector_type(4))) float f32x4;
typedef __attribute__((ext_vector_type(8))) __bf16 bf16x8;

// round-to-nearest-even f32 -> bf16 bits
static __device__ __forceinline__ unsigned int f2bf(float f) {
  unsigned int u = __float_as_uint(f);
  return (u + 0x7FFFu + ((u >> 16) & 1u)) >> 16;
}

// tanh(x) = 1 - 2/(1+e^{2x})
static __device__ __forceinline__ float fast_tanh(float x) {
  float e = __expf(2.f * x);
  return 1.f - 2.f * __builtin_amdgcn_rcpf(1.f + e);
}

// packed RNE f32x2 -> bf16x2 (single instruction)
static __device__ __forceinline__ unsigned int cvt_pk_bf16(float lo, float hi) {
  unsigned int r;
  asm("v_cvt_pk_bf16_f32 %0, %1, %2" : "=v"(r) : "v"(lo), "v"(hi));
  return r;
}

// ---------------------------------------------------------------------------
// Merged projections: pe[r][i] = enc[r][:] . W1[i][0:512]   (r < 1024)
//                     pd[r][i] = dec[r][:] . W1[i][512:1024] (r < 400)
// ---------------------------------------------------------------------------
__global__ __launch_bounds__(256) void proj_kernel(
    const float* __restrict__ enc, const float* __restrict__ dec,
    const float* __restrict__ W1, float* __restrict__ pe, float* __restrict__ pd) {
  __shared__ float As[64][17];
  __shared__ float Bs[64][17];
  const int bx = blockIdx.x;
  const float* A;
  float* P;
  int Mrows, colOff, row0;
  if (bx < 16) { A = enc; P = pe; Mrows = NB * NT; colOff = 0;  row0 = bx * 64; }
  else         { A = dec; P = pd; Mrows = NB * NU; colOff = NH; row0 = (bx - 16) * 64; }
  const int col0 = blockIdx.y * 64;
  const int tx = threadIdx.x;
  const int tr = tx >> 4, tc = tx & 15;
  const int lr = tx >> 2, lc = (tx & 3) * 4;
  float acc[4][4] = {};
  for (int k0 = 0; k0 < NH; k0 += 16) {
    float4 av = make_float4(0.f, 0.f, 0.f, 0.f);
    if (row0 + lr < Mrows)
      av = *(const float4*)(A + (size_t)(row0 + lr) * NH + k0 + lc);
    float4 bv = *(const float4*)(W1 + (size_t)(col0 + lr) * (NH + NH) + colOff + k0 + lc);
    As[lr][lc] = av.x; As[lr][lc + 1] = av.y; As[lr][lc + 2] = av.z; As[lr][lc + 3] = av.w;
    Bs[lr][lc] = bv.x; Bs[lr][lc + 1] = bv.y; Bs[lr][lc + 2] = bv.z; Bs[lr][lc + 3] = bv.w;
    __syncthreads();
#pragma unroll
    for (int kk = 0; kk < 16; ++kk) {
      float a4[4], b4[4];
#pragma unroll
      for (int i = 0; i < 4; ++i) { a4[i] = As[tr * 4 + i][kk]; b4[i] = Bs[tc * 4 + i][kk]; }
#pragma unroll
      for (int i = 0; i < 4; ++i)
#pragma unroll
        for (int j = 0; j < 4; ++j) acc[i][j] = fmaf(a4[i], b4[j], acc[i][j]);
    }
    __syncthreads();
  }
#pragma unroll
  for (int i = 0; i < 4; ++i) {
    int r = row0 + tr * 4 + i;
    if (r < Mrows) {
#pragma unroll
      for (int j = 0; j < 4; ++j)
        P[(size_t)r * NI + col0 + tc * 4 + j] = acc[i][j];
    }
  }
}

// ---------------------------------------------------------------------------
// W2 f32 -> bf16, PRE-FRAGGED for BK=32 direct-to-reg fragment loads:
// chunk g (16B) = [nt 4][kt 16][cb 16][lq 4][lr 16] ->
//   v = nt*256 + cb*16 + lr,  k = kt*32 + lq*8
// ---------------------------------------------------------------------------
__global__ __launch_bounds__(256) void cvt_w2_frag_kernel(
    const float* __restrict__ W2, unsigned short* __restrict__ w2f) {
  int g = blockIdx.x * 256 + threadIdx.x;      // 65536 chunks
  int lr = g & 15, lq = (g >> 4) & 3;
  int cb = (g >> 6) & 15, kt = (g >> 10) & 15, nt = (g >> 14) & 3;
  int v = nt * 256 + cb * 16 + lr;
  int k = kt * 32 + lq * 8;
  const float* src = W2 + (size_t)v * NI + k;
  float4 a = *(const float4*)src;
  float4 b = *(const float4*)(src + 4);
  uint4 o;
  o.x = f2bf(a.x) | (f2bf(a.y) << 16);
  o.y = f2bf(a.z) | (f2bf(a.w) << 16);
  o.z = f2bf(b.x) | (f2bf(b.y) << 16);
  o.w = f2bf(b.z) | (f2bf(b.w) << 16);
  *(uint4*)(w2f + (size_t)g * 8) = o;
}

// ---------------------------------------------------------------------------
// Fused joint GEMM, barrier-free K-loop, tanh exactly once, DEPTH-2 pipeline.
// Block: 512 thr / 8 waves (2M x 4N), 64 rows x FULL 1024 vocab.
// Phase 0: A panel tanh(pe+pd+b1) -> bf16 into 64 KB LDS (full K=512),
//          phys slot = g8 ^ (row&7). One barrier total.
// K-loop (64 steps of BK=32; np = step>>4, kt = step&15), unrolled x4 with
// TWO register B-sets each holding TWO steps (8 x bf16x8 = 32 VGPR/set):
//   COMPUTE2(A, g); LOADB2(A, g+4); COMPUTE2(B, g+2); LOADB2(B, g+6)
// -> a set's first use trails its issue by >=16 MFMA + a load-set (~600 cy),
// covering L2 latency; compiler emits counted vmcnt automatically.
// launch_bounds(512,4): <=128 VGPR -> 4 waves/SIMD + 2 blocks/CU (64KB LDS).
// Epilogue per vocab panel (kt==15): +b2, fp32 stores, re-zero acc.
// ---------------------------------------------------------------------------
__global__ __launch_bounds__(512, 4) void fused_joint_kernel(
    const float* __restrict__ pe, const float* __restrict__ pd,
    const float* __restrict__ b1, const unsigned short* __restrict__ w2f,
    const float* __restrict__ b2, float* __restrict__ out) {
  __shared__ unsigned char ldsA[65536];    // 64 rows x 512 k bf16, swizzled
  const int tx = threadIdx.x;
  const int R0 = blockIdx.x * 64;
  const int lane = tx & 63, wid = tx >> 6;
  const int wr = wid >> 2, wc = wid & 3;   // 2M x 4N; wave tile 32 x 64
  const int lr = lane & 15, lq = lane >> 4;

  // B fragment base: chunk = G*1024 + (wc*4+nf)*64 + lq*16 + lr (16B each)
  const unsigned short* w2base = w2f + ((size_t)(wc * 4) * 64 + lq * 16 + lr) * 8;

  // load B for steps G and G+1 into one 8-frag set
#define LOADB2(DST, G) do {                                                   \
    const unsigned short* s_ = w2base + ((size_t)(G) << 13);                  \
    DST##0 = *(const bf16x8*)(s_);                                            \
    DST##1 = *(const bf16x8*)(s_ + 512);                                      \
    DST##2 = *(const bf16x8*)(s_ + 1024);                                     \
    DST##3 = *(const bf16x8*)(s_ + 1536);                                     \
    DST##4 = *(const bf16x8*)(s_ + 8192);                                     \
    DST##5 = *(const bf16x8*)(s_ + 8704);                                     \
    DST##6 = *(const bf16x8*)(s_ + 9216);                                     \
    DST##7 = *(const bf16x8*)(s_ + 9728);                                     \
  } while (0)

  bf16x8 sA0, sA1, sA2, sA3, sA4, sA5, sA6, sA7;
  bf16x8 sB0, sB1, sB2, sB3, sB4, sB5, sB6, sB7;
  LOADB2(sA, 0);                           // steps 0,1 — in flight thru phase 0
  LOADB2(sB, 2);                           // steps 2,3

  // ---- Phase 0: A panel (64 x 512) = tanh(pe+pd+b1) -> ldsA ----
#pragma unroll 2
  for (int pass = 0; pass < 8; ++pass) {
    int idx = pass * 512 + tx;             // 4096 granules of 8 elems
    int row = idx >> 6;                    // 0..63
    int g8 = idx & 63;                     // granule within row
    int i0 = g8 * 8;
    int grow = R0 + row;
    int b = grow / (NT * NU);
    int rem = grow - b * (NT * NU);
    int t = rem / NU;
    int u = rem - t * NU;
    const float* peP = pe + (size_t)(b * NT + t) * NI + i0;
    const float* pdP = pd + (size_t)(b * NU + u) * NI + i0;
    float4 p0 = *(const float4*)peP, p1 = *(const float4*)(peP + 4);
    float4 q0 = *(const float4*)pdP, q1 = *(const float4*)(pdP + 4);
    float4 c0 = *(const float4*)(b1 + i0), c1 = *(const float4*)(b1 + i0 + 4);
    uint4 pk;
    pk.x = cvt_pk_bf16(fast_tanh(p0.x + q0.x + c0.x), fast_tanh(p0.y + q0.y + c0.y));
    pk.y = cvt_pk_bf16(fast_tanh(p0.z + q0.z + c0.z), fast_tanh(p0.w + q0.w + c0.w));
    pk.z = cvt_pk_bf16(fast_tanh(p1.x + q1.x + c1.x), fast_tanh(p1.y + q1.y + c1.y));
    pk.w = cvt_pk_bf16(fast_tanh(p1.z + q1.z + c1.z), fast_tanh(p1.w + q1.w + c1.w));
    *(uint4*)(ldsA + row * 1024 + ((g8 ^ (row & 7)) << 4)) = pk;
  }
  __syncthreads();                         // the ONLY barrier

  f32x4 acc[2][4];
#pragma unroll
  for (int mf = 0; mf < 2; ++mf)
#pragma unroll
    for (int nf = 0; nf < 4; ++nf)
#pragma unroll
      for (int z = 0; z < 4; ++z) acc[mf][nf][z] = 0.f;

  // one K-step: 2 ds_read (A frags) + 8 MFMA (+ per-panel epilogue)
#define STEP(B0, B1, B2, B3, G) do {                                          \
    const int kt_ = (G) & 15;                                                 \
    bf16x8 af_[2];                                                            \
    _Pragma("unroll")                                                         \
    for (int mf = 0; mf < 2; ++mf) {                                          \
      int row_ = wr * 32 + mf * 16 + lr;                                      \
      af_[mf] = *(const bf16x8*)(ldsA + row_ * 1024 +                         \
                                 (((kt_ * 4 + lq) ^ (lr & 7)) << 4));         \
    }                                                                         \
    __builtin_amdgcn_s_setprio(1);                                            \
    _Pragma("unroll")                                                         \
    for (int mf = 0; mf < 2; ++mf) {                                          \
      acc[mf][0] = __builtin_amdgcn_mfma_f32_16x16x32_bf16(af_[mf], B0, acc[mf][0], 0, 0, 0); \
      acc[mf][1] = __builtin_amdgcn_mfma_f32_16x16x32_bf16(af_[mf], B1, acc[mf][1], 0, 0, 0); \
      acc[mf][2] = __builtin_amdgcn_mfma_f32_16x16x32_bf16(af_[mf], B2, acc[mf][2], 0, 0, 0); \
      acc[mf][3] = __builtin_amdgcn_mfma_f32_16x16x32_bf16(af_[mf], B3, acc[mf][3], 0, 0, 0); \
    }                                                                         \
    __builtin_amdgcn_s_setprio(0);                                            \
    if (kt_ == 15) {                                                          \
      const int np_ = (G) >> 4;                                               \
      _Pragma("unroll")                                                       \
      for (int nf = 0; nf < 4; ++nf) {                                        \
        int col_ = np_ * 256 + wc * 64 + nf * 16 + lr;                        \
        float bb_ = b2[col_];                                                 \
        _Pragma("unroll")                                                     \
        for (int mf = 0; mf < 2; ++mf) {                                      \
          _Pragma("unroll")                                                   \
          for (int j = 0; j < 4; ++j) {                                       \
            int grow_ = R0 + wr * 32 + mf * 16 + lq * 4 + j;                  \
            out[(size_t)grow_ * NV + col_] = acc[mf][nf][j] + bb_;            \
            acc[mf][nf][j] = 0.f;                                             \
          }                                                                   \
        }                                                                     \
      }                                                                       \
    }                                                                         \
  } while (0)

  for (int g = 0; g < 64; g += 4) {
    STEP(sA0, sA1, sA2, sA3, g);
    STEP(sA4, sA5, sA6, sA7, g + 1);
    if (g + 4 < 64) LOADB2(sA, g + 4);     // in flight across next 2 steps
    STEP(sB0, sB1, sB2, sB3, g + 2);
    STEP(sB4, sB5, sB6, sB7, g + 3);
    if (g + 6 < 64) LOADB2(sB, g + 6);
  }
#undef STEP
#undef LOADB2
}

extern "C" void kernel_launch(void* const* d_in, const int* in_sizes, int n_in,
                              void* d_out, int out_size, void* d_ws, size_t ws_size,
                              hipStream_t stream) {
  const float* enc = (const float*)d_in[0];
  const float* dec = (const float*)d_in[1];
  const float* W1  = (const float*)d_in[2];
  const float* b1  = (const float*)d_in[3];
  const float* W2  = (const float*)d_in[4];
  const float* b2  = (const float*)d_in[5];
  float* out = (float*)d_out;
  char* ws = (char*)d_ws;

  float* pe = (float*)ws;                                   // 2 MB
  float* pd = (float*)(ws + (2u << 20));                    // 0.8 MB
  unsigned short* w2f = (unsigned short*)(ws + (3u << 20)); // 1 MB, fragged

  proj_kernel<<<dim3(23, 8), 256, 0, stream>>>(enc, dec, W1, pe, pd);
  cvt_w2_frag_kernel<<<256, 256, 0, stream>>>(W2, w2f);
  fused_joint_kernel<<<MROWS / 64, 512, 0, stream>>>(pe, pd, b1, w2f, b2, out);
}

// Round 15
// 258.999 us; speedup vs baseline: 1.2878x; 1.0135x over previous
//
#include <hip/hip_runtime.h>
#include <hip/hip_bf16.h>

// Problem constants
#define NB 4
#define NT 256
#define NU 100
#define NH 512      // H_ENC = H_DEC = 512
#define NI 512      // INNER
#define NV 1024     // VOCAB
#define MROWS (NB * NT * NU)   // 102400 joint rows

typedef __attribute__((ext_vector_type(16))) float f32x16;
typedef __attribute__((ext_vector_type(8))) __bf16 bf16x8;

// round-to-nearest-even f32 -> bf16 bits
static __device__ __forceinline__ unsigned int f2bf(float f) {
  unsigned int u = __float_as_uint(f);
  return (u + 0x7FFFu + ((u >> 16) & 1u)) >> 16;
}

// tanh(x) = 1 - 2/(1+e^{2x})
static __device__ __forceinline__ float fast_tanh(float x) {
  float e = __expf(2.f * x);
  return 1.f - 2.f * __builtin_amdgcn_rcpf(1.f + e);
}

// packed RNE f32x2 -> bf16x2 (single instruction)
static __device__ __forceinline__ unsigned int cvt_pk_bf16(float lo, float hi) {
  unsigned int r;
  asm("v_cvt_pk_bf16_f32 %0, %1, %2" : "=v"(r) : "v"(lo), "v"(hi));
  return r;
}

// ---------------------------------------------------------------------------
// Merged prep kernel. Grid (55, 8):
//  bx < 23: projections  pe[r][i] = enc[r][:] . W1[i][0:512]     (r < 1024)
//                        pd[r][i] = dec[r][:] . W1[i][512:1024]  (r < 400)
//  bx >= 23: W2 f32 -> bf16 pre-fragged for 32x32x16 B operands:
//    chunk c (16B) = [np 4][ks 32][ntl 8][lane 64]:
//      col = np*256 + ntl*32 + (lane&31),  k = ks*16 + (lane>>5)*8
// ---------------------------------------------------------------------------
__global__ __launch_bounds__(256) void prep_kernel(
    const float* __restrict__ enc, const float* __restrict__ dec,
    const float* __restrict__ W1, const float* __restrict__ W2,
    float* __restrict__ pe, float* __restrict__ pd,
    unsigned short* __restrict__ w2g) {
  const int bx = blockIdx.x;
  const int tx = threadIdx.x;
  if (bx >= 23) {
    int c = ((bx - 23) * 8 + blockIdx.y) * 256 + tx;  // 65536 chunks
    int lane = c & 63, ntl = (c >> 6) & 7, ks = (c >> 9) & 31, np = c >> 14;
    int col = np * 256 + ntl * 32 + (lane & 31);
    int k = ks * 16 + (lane >> 5) * 8;
    const float* src = W2 + (size_t)col * NI + k;
    float4 a = *(const float4*)src;
    float4 b = *(const float4*)(src + 4);
    uint4 o;
    o.x = f2bf(a.x) | (f2bf(a.y) << 16);
    o.y = f2bf(a.z) | (f2bf(a.w) << 16);
    o.z = f2bf(b.x) | (f2bf(b.y) << 16);
    o.w = f2bf(b.z) | (f2bf(b.w) << 16);
    *(uint4*)(w2g + (size_t)c * 8) = o;
    return;
  }
  __shared__ float As[64][17];
  __shared__ float Bs[64][17];
  const float* A;
  float* P;
  int Mrows, colOff, row0;
  if (bx < 16) { A = enc; P = pe; Mrows = NB * NT; colOff = 0;  row0 = bx * 64; }
  else         { A = dec; P = pd; Mrows = NB * NU; colOff = NH; row0 = (bx - 16) * 64; }
  const int col0 = blockIdx.y * 64;
  const int tr = tx >> 4, tc = tx & 15;
  const int lr = tx >> 2, lc = (tx & 3) * 4;
  float acc[4][4] = {};
  for (int k0 = 0; k0 < NH; k0 += 16) {
    float4 av = make_float4(0.f, 0.f, 0.f, 0.f);
    if (row0 + lr < Mrows)
      av = *(const float4*)(A + (size_t)(row0 + lr) * NH + k0 + lc);
    float4 bv = *(const float4*)(W1 + (size_t)(col0 + lr) * (NH + NH) + colOff + k0 + lc);
    As[lr][lc] = av.x; As[lr][lc + 1] = av.y; As[lr][lc + 2] = av.z; As[lr][lc + 3] = av.w;
    Bs[lr][lc] = bv.x; Bs[lr][lc + 1] = bv.y; Bs[lr][lc + 2] = bv.z; Bs[lr][lc + 3] = bv.w;
    __syncthreads();
#pragma unroll
    for (int kk = 0; kk < 16; ++kk) {
      float a4[4], b4[4];
#pragma unroll
      for (int i = 0; i < 4; ++i) { a4[i] = As[tr * 4 + i][kk]; b4[i] = Bs[tc * 4 + i][kk]; }
#pragma unroll
      for (int i = 0; i < 4; ++i)
#pragma unroll
        for (int j = 0; j < 4; ++j) acc[i][j] = fmaf(a4[i], b4[j], acc[i][j]);
    }
    __syncthreads();
  }
#pragma unroll
  for (int i = 0; i < 4; ++i) {
    int r = row0 + tr * 4 + i;
    if (r < Mrows) {
#pragma unroll
      for (int j = 0; j < 4; ++j)
        P[(size_t)r * NI + col0 + tc * 4 + j] = acc[i][j];
    }
  }
}

// ---------------------------------------------------------------------------
// Fused joint GEMM: barrier-free K-loop, tanh once, 32x32x16 MFMA, ring-4
// register B pipeline.
// Block: 512 thr / 8 waves (2M x 4N), 64 rows x FULL 1024 vocab.
// Wave tile 32 rows x 64 cols = 2 x (32x32) acc tiles (2 x f32x16 = 32 VGPR).
// Phase 0: A panel tanh(pe+pd+b1) -> 64 KB LDS (full K), granule swizzle
//          g8 ^ (row&7). ONE barrier total.
// K-loop: 128 steps of K=16 (np = g>>5 vocab panel, ks = g&31).
//   Per step: 1 ds_read_b128 (A frag) + 2 MFMA(32x32x16) + 2 B loads for
//   step g+4 into a 4-set register ring (use trails load by 3 steps -> L2
//   latency fully covered; compiler emits counted vmcnt).
// launch_bounds(512,4): ~95 VGPR -> 4 waves/SIMD; 64 KB LDS -> 2 blocks/CU.
// Epilogue per vocab panel (ks==31): +b2, fp32 stores
//   (C/D map: col=lane&31, row=(reg&3)+8*(reg>>2)+4*(lane>>5); m74/m101).
// ---------------------------------------------------------------------------
__global__ __launch_bounds__(512, 4) void fused_joint_kernel(
    const float* __restrict__ pe, const float* __restrict__ pd,
    const float* __restrict__ b1, const unsigned short* __restrict__ w2g,
    const float* __restrict__ b2, float* __restrict__ out) {
  __shared__ unsigned char ldsA[65536];    // 64 rows x 512 k bf16, swizzled
  const int tx = threadIdx.x;
  const int R0 = blockIdx.x * 64;
  const int lane = tx & 63, wid = tx >> 6;
  const int wr = wid >> 2, wc = wid & 3;   // 2M x 4N; wave tile 32 x 64
  const int l31 = lane & 31, lh = lane >> 5;

  // B frag bases: chunk = g*512 + (wc*2+j)*64 + lane  (16B chunks)
  const unsigned char* w2p = (const unsigned char*)w2g;
  const unsigned char* bBase0 = w2p + ((wc * 2 + 0) * 64 + lane) * 16;
  const unsigned char* bBase1 = w2p + ((wc * 2 + 1) * 64 + lane) * 16;

#define LOADB(SET, G) do {                                                    \
    SET##0 = *(const bf16x8*)(bBase0 + ((size_t)(G) << 13));                  \
    SET##1 = *(const bf16x8*)(bBase1 + ((size_t)(G) << 13));                  \
  } while (0)

  bf16x8 s00, s01, s10, s11, s20, s21, s30, s31;
  LOADB(s0, 0); LOADB(s1, 1); LOADB(s2, 2); LOADB(s3, 3);  // thru phase 0

  // ---- Phase 0: A panel (64 x 512) = tanh(pe+pd+b1) -> ldsA ----
#pragma unroll 2
  for (int pass = 0; pass < 8; ++pass) {
    int idx = pass * 512 + tx;             // 4096 granules of 8 elems
    int row = idx >> 6;                    // 0..63
    int g8 = idx & 63;                     // granule within row
    int i0 = g8 * 8;
    int grow = R0 + row;
    int b = grow / (NT * NU);
    int rem = grow - b * (NT * NU);
    int t = rem / NU;
    int u = rem - t * NU;
    const float* peP = pe + (size_t)(b * NT + t) * NI + i0;
    const float* pdP = pd + (size_t)(b * NU + u) * NI + i0;
    float4 p0 = *(const float4*)peP, p1 = *(const float4*)(peP + 4);
    float4 q0 = *(const float4*)pdP, q1 = *(const float4*)(pdP + 4);
    float4 c0 = *(const float4*)(b1 + i0), c1 = *(const float4*)(b1 + i0 + 4);
    uint4 pk;
    pk.x = cvt_pk_bf16(fast_tanh(p0.x + q0.x + c0.x), fast_tanh(p0.y + q0.y + c0.y));
    pk.y = cvt_pk_bf16(fast_tanh(p0.z + q0.z + c0.z), fast_tanh(p0.w + q0.w + c0.w));
    pk.z = cvt_pk_bf16(fast_tanh(p1.x + q1.x + c1.x), fast_tanh(p1.y + q1.y + c1.y));
    pk.w = cvt_pk_bf16(fast_tanh(p1.z + q1.z + c1.z), fast_tanh(p1.w + q1.w + c1.w));
    *(uint4*)(ldsA + row * 1024 + ((g8 ^ (row & 7)) << 4)) = pk;
  }
  __syncthreads();                         // the ONLY barrier

  f32x16 acc0, acc1;
#pragma unroll
  for (int z = 0; z < 16; ++z) { acc0[z] = 0.f; acc1[z] = 0.f; }

  // A frag base: row = wr*32 + l31; addr = row*1024 + ((gi ^ (row&7))<<4),
  // gi = (g&31)*2 + lh
  const int aRowBase = (wr * 32 + l31) * 1024;
  const int rx = l31 & 7;

#define STEP(SET, G) do {                                                     \
    const int ks_ = (G) & 31;                                                 \
    bf16x8 af_ = *(const bf16x8*)(ldsA + aRowBase +                           \
                                  (((ks_ * 2 + lh) ^ rx) << 4));              \
    __builtin_amdgcn_s_setprio(1);                                            \
    acc0 = __builtin_amdgcn_mfma_f32_32x32x16_bf16(af_, SET##0, acc0, 0, 0, 0); \
    acc1 = __builtin_amdgcn_mfma_f32_32x32x16_bf16(af_, SET##1, acc1, 0, 0, 0); \
    __builtin_amdgcn_s_setprio(0);                                            \
    if (ks_ == 31) {                                                          \
      const int np_ = (G) >> 5;                                               \
      int c0_ = np_ * 256 + wc * 64 + l31;                                    \
      float bb0_ = b2[c0_];                                                   \
      float bb1_ = b2[c0_ + 32];                                              \
      _Pragma("unroll")                                                       \
      for (int r_ = 0; r_ < 16; ++r_) {                                       \
        int grow_ = R0 + wr * 32 + (r_ & 3) + 8 * (r_ >> 2) + 4 * lh;         \
        float* op_ = out + (size_t)grow_ * NV + c0_;                          \
        op_[0]  = acc0[r_] + bb0_;                                            \
        op_[32] = acc1[r_] + bb1_;                                            \
        acc0[r_] = 0.f;                                                       \
        acc1[r_] = 0.f;                                                       \
      }                                                                       \
    }                                                                         \
  } while (0)

  for (int g = 0; g < 128; g += 4) {
    STEP(s0, g);     if (g + 4 < 128) LOADB(s0, g + 4);
    STEP(s1, g + 1); if (g + 5 < 128) LOADB(s1, g + 5);
    STEP(s2, g + 2); if (g + 6 < 128) LOADB(s2, g + 6);
    STEP(s3, g + 3); if (g + 7 < 128) LOADB(s3, g + 7);
  }
#undef STEP
#undef LOADB
}

extern "C" void kernel_launch(void* const* d_in, const int* in_sizes, int n_in,
                              void* d_out, int out_size, void* d_ws, size_t ws_size,
                              hipStream_t stream) {
  const float* enc = (const float*)d_in[0];
  const float* dec = (const float*)d_in[1];
  const float* W1  = (const float*)d_in[2];
  const float* b1  = (const float*)d_in[3];
  const float* W2  = (const float*)d_in[4];
  const float* b2  = (const float*)d_in[5];
  float* out = (float*)d_out;
  char* ws = (char*)d_ws;

  float* pe = (float*)ws;                                   // 2 MB
  float* pd = (float*)(ws + (2u << 20));                    // 0.8 MB
  unsigned short* w2g = (unsigned short*)(ws + (3u << 20)); // 1 MB, fragged

  prep_kernel<<<dim3(55, 8), 256, 0, stream>>>(enc, dec, W1, W2, pe, pd, w2g);
  fused_joint_kernel<<<MROWS / 64, 512, 0, stream>>>(pe, pd, b1, w2g, b2, out);
}